// Round 3
// baseline (1456.395 us; speedup 1.0000x reference)
//
#include <hip/hip_runtime.h>

#define PER  149796
#define HDIM 64
#define EDIM 32
#define MAXC 16
#define NIOU 192

__device__ __forceinline__ float sigf(float x){ return 1.0f/(1.0f+__expf(-x)); }
__device__ __forceinline__ float tanh_f(float x){
  float ax = fabsf(x);
  float e  = __expf(-2.0f*ax);
  float t  = (1.0f - e)/(1.0f + e);
  return x < 0.0f ? -t : t;
}

// ---- tables: embWiou[v][192] = biou + Wiou.emb[v]; embWf[v][64] = bf + Wf.emb[v]
__global__ __launch_bounds__(256) void table_kernel(
    const float* __restrict__ emb, const float* __restrict__ Wiou, const float* __restrict__ biou,
    const float* __restrict__ Wf, const float* __restrict__ bf,
    float* __restrict__ embWiou, float* __restrict__ embWf)
{
  int v = blockIdx.x;           // 0..1023
  int m = threadIdx.x;          // 0..255 : 0..191 -> iou, 192..255 -> f
  const float* x = emb + (size_t)v*EDIM;   // v uniform -> scalar loads
  if (m < NIOU){
    float a = biou[m];
    #pragma unroll
    for (int e=0;e<EDIM;e++) a += Wiou[m*EDIM+e]*x[e];
    embWiou[(size_t)v*NIOU + m] = a;
  } else {
    int mm = m - NIOU;
    float a = bf[mm];
    #pragma unroll
    for (int e=0;e<EDIM;e++) a += Wf[mm*EDIM+e]*x[e];
    embWf[(size_t)v*HDIM + mm] = a;
  }
}

// ---- transpose U matrices: UT[k][m] = U[m][k]
__global__ void transpose_kernel(const float* __restrict__ Uiou, const float* __restrict__ Uf,
                                 float* __restrict__ UiouT, float* __restrict__ UfT)
{
  for (int i = threadIdx.x; i < NIOU*HDIM; i += 256){
    int gm = i / HDIM, k = i % HDIM;
    UiouT[k*NIOU + gm] = Uiou[i];
  }
  for (int i = threadIdx.x; i < HDIM*HDIM; i += 256){
    int mm = i / HDIM, k = i % HDIM;
    UfT[k*HDIM + mm] = Uf[i];
  }
}

// ---- leaves (depth 7): pure elementwise from table
__global__ __launch_bounds__(256) void leaf_kernel(
    const int* __restrict__ tok, const float* __restrict__ embWiou,
    float* __restrict__ hC, float* __restrict__ cC)
{
  int gid = blockIdx.x*blockDim.x + threadIdx.x;   // over PER*16 float4 groups
  if (gid >= PER*16) return;
  int j = gid >> 4, sub = gid & 15;
  int t = tok[1 + 6*PER + j];
  const float* row = embWiou + (size_t)t*NIOU;
  float4 i4 = *(const float4*)(row + sub*4);
  float4 o4 = *(const float4*)(row + 64 + sub*4);
  float4 u4 = *(const float4*)(row + 128 + sub*4);
  float4 cv, hv;
  cv.x = sigf(i4.x)*tanh_f(u4.x); hv.x = sigf(o4.x)*tanh_f(cv.x);
  cv.y = sigf(i4.y)*tanh_f(u4.y); hv.y = sigf(o4.y)*tanh_f(cv.y);
  cv.z = sigf(i4.z)*tanh_f(u4.z); hv.z = sigf(o4.z)*tanh_f(cv.z);
  cv.w = sigf(i4.w)*tanh_f(u4.w); hv.w = sigf(o4.w)*tanh_f(cv.w);
  *(float4*)(cC + (size_t)j*HDIM + sub*4) = cv;
  *(float4*)(hC + (size_t)j*HDIM + sub*4) = hv;
}

// ---- child lists (1 int atomic per child); counts zeroed once, re-zeroed by node_kernel
__global__ __launch_bounds__(256) void build_kernel(
    const int* __restrict__ parent, int* __restrict__ counts, int* __restrict__ list,
    int coff, int poff)
{
  int jc = blockIdx.x*blockDim.x + threadIdx.x;
  if (jc >= PER) return;
  int jp = parent[coff+jc] - poff;
  int slot = atomicAdd(&counts[jp], 1);
  if (slot < MAXC) list[jp*MAXC + slot] = jc;
}

// ---- fch: one wave per block, Uf weights pinned in VGPRs
__global__ __launch_bounds__(64,4) void fch_kernel(
    const int* __restrict__ tok, const int* __restrict__ parent,
    const float* __restrict__ embWf, const float* __restrict__ UfT,
    const float* __restrict__ hP, const float* __restrict__ cP,
    float* __restrict__ fch, int coff)
{
  int m = threadIdx.x;
  float w[HDIM];
  #pragma unroll
  for (int k=0;k<HDIM;k++) w[k] = UfT[k*HDIM + m];
  #pragma unroll
  for (int k=0;k<HDIM;k++) asm volatile("" : "+v"(w[k]));
  for (int jc = blockIdx.x; jc < PER; jc += gridDim.x){
    int jp = __builtin_amdgcn_readfirstlane(parent[coff + jc]);
    int t  = __builtin_amdgcn_readfirstlane(tok[jp]);
    float acc = embWf[(size_t)t*HDIM + m];
    const float* hrow = hP + (size_t)jc*HDIM;            // wave-uniform row -> s_load
    #pragma unroll
    for (int k=0;k<HDIM;k++) acc += w[k]*hrow[k];
    float cc = cP[(size_t)jc*HDIM + m];
    fch[(size_t)jc*HDIM + m] = sigf(acc)*cc;
  }
}

// ---- node: one wave per block; 192 Uiou weights pinned in VGPRs
__global__ __launch_bounds__(64,2) void node_kernel(
    const int* __restrict__ tok, const float* __restrict__ embWiou,
    const float* __restrict__ UiouT,
    int* __restrict__ counts, const int* __restrict__ list,
    const float* __restrict__ fch, const float* __restrict__ hP,
    float* __restrict__ hC, float* __restrict__ cC, int loff)
{
  int m = threadIdx.x;
  float wI[HDIM], wO[HDIM], wU[HDIM];
  #pragma unroll
  for (int k=0;k<HDIM;k++){
    wI[k] = UiouT[k*NIOU       + m];
    wO[k] = UiouT[k*NIOU + 64  + m];
    wU[k] = UiouT[k*NIOU + 128 + m];
  }
  #pragma unroll
  for (int k=0;k<HDIM;k++) asm volatile("" : "+v"(wI[k]), "+v"(wO[k]), "+v"(wU[k]));
  for (int j = blockIdx.x; j < PER; j += gridDim.x){
    int t = __builtin_amdgcn_readfirstlane(tok[loff + j]);
    const float* trow = embWiou + (size_t)t*NIOU;
    float ai = trow[m], ao = trow[64+m], au = trow[128+m];
    float fa = 0.f;
    int nc = __builtin_amdgcn_readfirstlane(counts[j]);
    if (nc > MAXC) nc = MAXC;
    for (int s=0; s<nc; s++){
      int jc = __builtin_amdgcn_readfirstlane(list[j*MAXC + s]);
      fa += fch[(size_t)jc*HDIM + m];                    // coalesced
      const float* hrow = hP + (size_t)jc*HDIM;          // wave-uniform row -> s_load
      #pragma unroll
      for (int k=0;k<HDIM;k++){
        float hv = hrow[k];
        ai += wI[k]*hv; ao += wO[k]*hv; au += wU[k]*hv;
      }
    }
    if (m == 0) counts[j] = 0;                           // ready for next level's build
    float c = sigf(ai)*tanh_f(au) + fa;
    float h = sigf(ao)*tanh_f(c);
    cC[(size_t)j*HDIM + m] = c;
    hC[(size_t)j*HDIM + m] = h;
  }
}

// ---- root: fused f-gate + reduction over all level-1 children
__global__ __launch_bounds__(64,4) void rootfused_kernel(
    const int* __restrict__ tok, const float* __restrict__ embWf,
    const float* __restrict__ UfT,
    const float* __restrict__ hP, const float* __restrict__ cP,
    float* __restrict__ rootacc)
{
  int m = threadIdx.x;
  float w[HDIM];
  #pragma unroll
  for (int k=0;k<HDIM;k++) w[k] = UfT[k*HDIM + m];
  #pragma unroll
  for (int k=0;k<HDIM;k++) asm volatile("" : "+v"(w[k]));
  int t0 = __builtin_amdgcn_readfirstlane(tok[0]);
  float wfx = embWf[(size_t)t0*HDIM + m];
  float af = 0.f, ah = 0.f;
  for (int jc = blockIdx.x; jc < PER; jc += gridDim.x){
    const float* hrow = hP + (size_t)jc*HDIM;            // wave-uniform
    float acc = wfx;
    #pragma unroll
    for (int k=0;k<HDIM;k++) acc += w[k]*hrow[k];
    float cc = cP[(size_t)jc*HDIM + m];
    af += sigf(acc)*cc;
    ah += hrow[m];
  }
  atomicAdd(&rootacc[m],      af);
  atomicAdd(&rootacc[64 + m], ah);
}

__global__ void rootnode_kernel(
    const int* __restrict__ tok, const float* __restrict__ emb,
    const float* __restrict__ Wiou, const float* __restrict__ biou, const float* __restrict__ Uiou,
    const float* __restrict__ rootacc, float* __restrict__ out)
{
  int m = threadIdx.x;
  if (m >= HDIM) return;
  int t = tok[0];
  float ai=biou[m], ao=biou[HDIM+m], au=biou[2*HDIM+m];
  for (int e=0;e<EDIM;e++){
    float xe = emb[(size_t)t*EDIM+e];
    ai += Wiou[(size_t)m*EDIM+e]*xe;
    ao += Wiou[(size_t)(HDIM+m)*EDIM+e]*xe;
    au += Wiou[(size_t)(2*HDIM+m)*EDIM+e]*xe;
  }
  for (int k=0;k<HDIM;k++){
    float hv = rootacc[64+k];
    ai += Uiou[(size_t)m*HDIM+k]*hv;
    ao += Uiou[(size_t)(HDIM+m)*HDIM+k]*hv;
    au += Uiou[(size_t)(2*HDIM+m)*HDIM+k]*hv;
  }
  float c = sigf(ai)*tanh_f(au) + rootacc[m];
  out[m] = sigf(ao)*tanh_f(c);
}

extern "C" void kernel_launch(void* const* d_in, const int* in_sizes, int n_in,
                              void* d_out, int out_size, void* d_ws, size_t ws_size,
                              hipStream_t stream)
{
  const int*   tok    = (const int*)d_in[0];
  const int*   parent = (const int*)d_in[1];
  const float* emb    = (const float*)d_in[4];
  const float* Wiou   = (const float*)d_in[5];
  const float* biou   = (const float*)d_in[6];
  const float* Uiou   = (const float*)d_in[7];
  const float* Wf     = (const float*)d_in[8];
  const float* bf     = (const float*)d_in[9];
  const float* Uf     = (const float*)d_in[10];
  float* out = (float*)d_out;

  float* ws = (float*)d_ws;
  size_t SZ = (size_t)PER*HDIM;
  float* hA      = ws;
  float* cA      = ws + SZ;
  float* hB      = ws + 2*SZ;
  float* cB      = ws + 3*SZ;
  float* fch     = ws + 4*SZ;
  float* embWiou = ws + 5*SZ;                 // 1024*192
  float* embWf   = embWiou + 1024*NIOU;       // 1024*64
  float* UiouT   = embWf + 1024*HDIM;         // 192*64
  float* UfT     = UiouT + NIOU*HDIM;         // 64*64
  float* rootacc = UfT + HDIM*HDIM;           // 128
  int*   counts  = (int*)(rootacc + 128);     // PER
  int*   list    = counts + PER;              // PER*MAXC

  const int B = 256;
  const int gPER   = (PER + B - 1)/B;
  const int gLEAF  = (PER*16 + B - 1)/B;

  hipMemsetAsync(counts, 0, (size_t)PER*sizeof(int), stream);
  hipMemsetAsync(rootacc, 0, 128*sizeof(float), stream);
  table_kernel<<<1024, B, 0, stream>>>(emb, Wiou, biou, Wf, bf, embWiou, embWf);
  transpose_kernel<<<1, B, 0, stream>>>(Uiou, Uf, UiouT, UfT);

  // depth 7 (leaves) -> A
  leaf_kernel<<<gLEAF, B, 0, stream>>>(tok, embWiou, hA, cA);

  float* hPrev=hA; float* cPrev=cA; float* hCur=hB; float* cCur=cB;
  for (int d=6; d>=1; --d){
    int poff = 1 + (d-1)*PER;
    int coff = 1 + d*PER;
    build_kernel<<<gPER, B, 0, stream>>>(parent, counts, list, coff, poff);
    fch_kernel  <<<4096, 64, 0, stream>>>(tok, parent, embWf, UfT, hPrev, cPrev, fch, coff);
    node_kernel <<<2048, 64, 0, stream>>>(tok, embWiou, UiouT, counts, list, fch,
                                          hPrev, hCur, cCur, poff);
    float* th=hPrev; hPrev=hCur; hCur=th;
    float* tc=cPrev; cPrev=cCur; cCur=tc;
  }

  // depth 0 (root): all level-1 nodes are its children (fused f-gate + reduction)
  rootfused_kernel<<<2048, 64, 0, stream>>>(tok, embWf, UfT, hPrev, cPrev, rootacc);
  rootnode_kernel<<<1, 64, 0, stream>>>(tok, emb, Wiou, biou, Uiou, rootacc, out);
}

// Round 4
// 937.860 us; speedup vs baseline: 1.5529x; 1.5529x over previous
//
#include <hip/hip_runtime.h>

#define PER  149796
#define HDIM 64
#define EDIM 32
#define MAXC 16
#define NIOU 192

typedef _Float16 f16;
typedef _Float16 f16x8 __attribute__((ext_vector_type(8)));
typedef _Float16 f16x4 __attribute__((ext_vector_type(4)));
typedef float    f32x4 __attribute__((ext_vector_type(4)));

__device__ __forceinline__ float sigf(float x){ return 1.0f/(1.0f+__expf(-x)); }
__device__ __forceinline__ float tanh_f(float x){
  float ax = fabsf(x);
  float e  = __expf(-2.0f*ax);
  float t  = (1.0f - e)/(1.0f + e);
  return x < 0.0f ? -t : t;
}

// ---- tables: embWiou[v][192] = biou + Wiou.emb[v]; embWf[v][64] = bf + Wf.emb[v]
__global__ __launch_bounds__(256) void table_kernel(
    const float* __restrict__ emb, const float* __restrict__ Wiou, const float* __restrict__ biou,
    const float* __restrict__ Wf, const float* __restrict__ bf,
    float* __restrict__ embWiou, float* __restrict__ embWf)
{
  int v = blockIdx.x;
  int m = threadIdx.x;
  const float* x = emb + (size_t)v*EDIM;
  if (m < NIOU){
    float a = biou[m];
    #pragma unroll
    for (int e=0;e<EDIM;e++) a += Wiou[m*EDIM+e]*x[e];
    embWiou[(size_t)v*NIOU + m] = a;
  } else {
    int mm = m - NIOU;
    float a = bf[mm];
    #pragma unroll
    for (int e=0;e<EDIM;e++) a += Wf[mm*EDIM+e]*x[e];
    embWf[(size_t)v*HDIM + mm] = a;
  }
}

// ---- pack U matrices into MFMA B-fragment order (f16)
// B[k][n] layout for mfma_f32_16x16x32_f16: lane L holds n=L&15, k=(L>>4)*8+j, j=0..7
// Bf  : [s<2][t<4 ][L<64][j<8]  with k = s*32 + (L>>4)*8 + j, n = t*16 + (L&15), val = Uf[n*64+k]
// Biou: [s<2][t<12][L<64][j<8]  same, val = Uiou[n*64+k]
__global__ void pack_kernel(const float* __restrict__ Uf, const float* __restrict__ Uiou,
                            f16* __restrict__ Bf, f16* __restrict__ Biou)
{
  for (int i = threadIdx.x; i < 2*4*64*8; i += 256){
    int j = i & 7, L = (i>>3)&63, st = i>>9;
    int t = st & 3, s = st >> 2;
    int k = s*32 + (L>>4)*8 + j;
    int n = t*16 + (L&15);
    Bf[i] = (f16)Uf[n*HDIM + k];
  }
  for (int i = threadIdx.x; i < 2*12*64*8; i += 256){
    int j = i & 7, L = (i>>3)&63, st = i>>9;
    int t = st % 12, s = st / 12;
    int k = s*32 + (L>>4)*8 + j;
    int n = t*16 + (L&15);
    Biou[i] = (f16)Uiou[n*HDIM + k];
  }
}

// ---- leaves (depth 7): elementwise from table; h stored f16, c fp32
__global__ __launch_bounds__(256) void leaf_kernel(
    const int* __restrict__ tok, const float* __restrict__ embWiou,
    f16* __restrict__ hC, float* __restrict__ cC)
{
  int gid = blockIdx.x*blockDim.x + threadIdx.x;
  if (gid >= PER*16) return;
  int j = gid >> 4, sub = gid & 15;
  int t = tok[1 + 6*PER + j];
  const float* row = embWiou + (size_t)t*NIOU;
  float4 i4 = *(const float4*)(row + sub*4);
  float4 o4 = *(const float4*)(row + 64 + sub*4);
  float4 u4 = *(const float4*)(row + 128 + sub*4);
  float4 cv;
  cv.x = sigf(i4.x)*tanh_f(u4.x);
  cv.y = sigf(i4.y)*tanh_f(u4.y);
  cv.z = sigf(i4.z)*tanh_f(u4.z);
  cv.w = sigf(i4.w)*tanh_f(u4.w);
  f16x4 hv;
  hv.x = (f16)(sigf(o4.x)*tanh_f(cv.x));
  hv.y = (f16)(sigf(o4.y)*tanh_f(cv.y));
  hv.z = (f16)(sigf(o4.z)*tanh_f(cv.z));
  hv.w = (f16)(sigf(o4.w)*tanh_f(cv.w));
  *(float4*)(cC + (size_t)j*HDIM + sub*4) = cv;
  *(f16x4*)(hC + (size_t)j*HDIM + sub*4) = hv;
}

// ---- child lists (1 int atomic per child); counts zeroed once, re-zeroed by node_mfma
__global__ __launch_bounds__(256) void build_kernel(
    const int* __restrict__ parent, int* __restrict__ counts, int* __restrict__ list,
    int coff, int poff)
{
  int jc = blockIdx.x*blockDim.x + threadIdx.x;
  if (jc >= PER) return;
  int jp = parent[coff+jc] - poff;
  int slot = atomicAdd(&counts[jp], 1);
  if (slot < MAXC) list[jp*MAXC + slot] = jc;
}

// ---- fch: MFMA GEMM FC = sigf(Hc@Uf^T + wfx[parent]) * Cc
// wave handles 64 children (4 M-tiles of 16) x 64 outputs (4 N-tiles of 16), K=64 (2 steps)
__global__ __launch_bounds__(256) void fch_mfma(
    const int* __restrict__ tok, const int* __restrict__ parent,
    const float* __restrict__ embWf, const f16* __restrict__ Bfpack,
    const f16* __restrict__ Hc, const float* __restrict__ Cc,
    float* __restrict__ FC, int coff)
{
  int lane = threadIdx.x & 63;
  int wv   = threadIdx.x >> 6;
  int base = (blockIdx.x*4 + wv)*64;
  if (base >= PER) return;
  int q = lane >> 4, c16 = lane & 15;

  const f16x8* Bp = (const f16x8*)Bfpack;
  f16x8 B[2][4];
  #pragma unroll
  for (int s=0;s<2;s++)
    #pragma unroll
    for (int t=0;t<4;t++) B[s][t] = Bp[(s*4+t)*64 + lane];

  f32x4 acc[4][4];
  #pragma unroll
  for (int a=0;a<4;a++)
    #pragma unroll
    for (int b=0;b<4;b++) acc[a][b] = (f32x4){0.f,0.f,0.f,0.f};

  #pragma unroll
  for (int tm=0;tm<4;tm++){
    int row = base + tm*16 + c16;
    if (row > PER-1) row = PER-1;
    const f16x8* hp = (const f16x8*)(Hc + (size_t)row*HDIM);
    f16x8 A0 = hp[q];       // k = q*8..q*8+7
    f16x8 A1 = hp[4 + q];   // k = 32+q*8..
    #pragma unroll
    for (int nt=0;nt<4;nt++){
      acc[tm][nt] = __builtin_amdgcn_mfma_f32_16x16x32_f16(A0, B[0][nt], acc[tm][nt], 0,0,0);
      acc[tm][nt] = __builtin_amdgcn_mfma_f32_16x16x32_f16(A1, B[1][nt], acc[tm][nt], 0,0,0);
    }
  }
  // epilogue: D[row=q*4+r][col=c16] per tile
  #pragma unroll
  for (int tm=0;tm<4;tm++){
    #pragma unroll
    for (int r=0;r<4;r++){
      int child = base + tm*16 + q*4 + r;
      bool ok = child < PER;
      int cl = ok ? child : PER-1;
      int jp = parent[coff + cl];
      int tk = tok[jp];
      const float* wr = embWf + (size_t)tk*HDIM;
      #pragma unroll
      for (int nt=0;nt<4;nt++){
        int col = nt*16 + c16;
        float g = acc[tm][nt][r] + wr[col];
        float v = sigf(g) * Cc[(size_t)cl*HDIM + col];
        if (ok) FC[(size_t)child*HDIM + col] = v;
      }
    }
  }
}

// ---- node: gather children (Hsum->LDS f16, FA->LDS) then MFMA Hsum@Uiou^T + epilogue
// block = 4 waves x 16 parents = 64 parents
__global__ __launch_bounds__(256) void node_mfma(
    const int* __restrict__ tok, const float* __restrict__ embWiou,
    const f16* __restrict__ Bioupack,
    int* __restrict__ counts, const int* __restrict__ list,
    const float* __restrict__ FC, const f16* __restrict__ Hc,
    f16* __restrict__ Hp, float* __restrict__ Cp, int poff)
{
  __shared__ f16   Ah[64*72];
  __shared__ float FAs[64*68];
  int lane = threadIdx.x & 63;
  int wv   = threadIdx.x >> 6;
  int blockBase = blockIdx.x * 64;
  int p0 = wv*16;
  // phase 1: gather
  #pragma unroll 1
  for (int i=0;i<16;i++){
    int j = blockBase + p0 + i;
    float hs = 0.f, fa = 0.f;
    if (j < PER){
      int nc = __builtin_amdgcn_readfirstlane(counts[j]);
      if (nc > MAXC) nc = MAXC;
      for (int s=0;s<nc;s++){
        int jc = __builtin_amdgcn_readfirstlane(list[j*MAXC+s]);
        hs += (float)Hc[(size_t)jc*HDIM + lane];
        fa += FC[(size_t)jc*HDIM + lane];
      }
      if (lane == 0) counts[j] = 0;      // ready for next level's build
    }
    Ah[(p0+i)*72 + lane] = (f16)hs;
    FAs[(p0+i)*68 + lane] = fa;
  }
  __syncthreads();
  int q = lane>>4, c16 = lane&15;
  f16x8 A0 = *(const f16x8*)(Ah + (p0 + c16)*72 + q*8);
  f16x8 A1 = *(const f16x8*)(Ah + (p0 + c16)*72 + 32 + q*8);
  const f16x8* Bp = (const f16x8*)Bioupack;
  f32x4 acc[12];
  #pragma unroll
  for (int nt=0;nt<12;nt++) acc[nt] = (f32x4){0.f,0.f,0.f,0.f};
  #pragma unroll
  for (int nt=0;nt<12;nt++){
    f16x8 B0 = Bp[nt*64 + lane];
    f16x8 B1 = Bp[(12+nt)*64 + lane];
    acc[nt] = __builtin_amdgcn_mfma_f32_16x16x32_f16(A0, B0, acc[nt], 0,0,0);
    acc[nt] = __builtin_amdgcn_mfma_f32_16x16x32_f16(A1, B1, acc[nt], 0,0,0);
  }
  // epilogue
  #pragma unroll
  for (int r=0;r<4;r++){
    int prow = p0 + q*4 + r;
    int j = blockBase + prow;
    bool ok = j < PER;
    int jl = ok ? j : PER-1;
    int tk = tok[poff + jl];
    const float* tr = embWiou + (size_t)tk*NIOU;
    #pragma unroll
    for (int nt=0;nt<4;nt++){
      int col = nt*16 + c16;
      float ai = acc[nt][r]   + tr[col];
      float ao = acc[nt+4][r] + tr[64+col];
      float au = acc[nt+8][r] + tr[128+col];
      float fa = FAs[prow*68 + col];
      float cv = sigf(ai)*tanh_f(au) + fa;
      float hv = sigf(ao)*tanh_f(cv);
      if (ok){
        Cp[(size_t)j*HDIM + col] = cv;
        Hp[(size_t)j*HDIM + col] = (f16)hv;
      }
    }
  }
}

// ---- root reduction over all level-1 children
__global__ __launch_bounds__(256) void rootred_kernel(
    const float* __restrict__ FC, const f16* __restrict__ Hp, float* __restrict__ rootacc)
{
  int t = blockIdx.x*blockDim.x + threadIdx.x;
  int m = t & 63;
  int j0 = t >> 6;
  int jstep = (gridDim.x*blockDim.x) >> 6;
  float af=0.f, ah=0.f;
  for (int j=j0; j<PER; j+=jstep){
    af += FC[(size_t)j*HDIM + m];
    ah += (float)Hp[(size_t)j*HDIM + m];
  }
  __shared__ float red[256];
  red[threadIdx.x]=af; __syncthreads();
  if (threadIdx.x < 64) atomicAdd(&rootacc[m],    red[m]+red[64+m]+red[128+m]+red[192+m]);
  __syncthreads();
  red[threadIdx.x]=ah; __syncthreads();
  if (threadIdx.x < 64) atomicAdd(&rootacc[64+m], red[m]+red[64+m]+red[128+m]+red[192+m]);
}

__global__ void rootnode_kernel(
    const int* __restrict__ tok, const float* __restrict__ emb,
    const float* __restrict__ Wiou, const float* __restrict__ biou, const float* __restrict__ Uiou,
    const float* __restrict__ rootacc, float* __restrict__ out)
{
  int m = threadIdx.x;
  if (m >= HDIM) return;
  int t = tok[0];
  float ai=biou[m], ao=biou[HDIM+m], au=biou[2*HDIM+m];
  for (int e=0;e<EDIM;e++){
    float xe = emb[(size_t)t*EDIM+e];
    ai += Wiou[(size_t)m*EDIM+e]*xe;
    ao += Wiou[(size_t)(HDIM+m)*EDIM+e]*xe;
    au += Wiou[(size_t)(2*HDIM+m)*EDIM+e]*xe;
  }
  for (int k=0;k<HDIM;k++){
    float hv = rootacc[64+k];
    ai += Uiou[(size_t)m*HDIM+k]*hv;
    ao += Uiou[(size_t)(HDIM+m)*HDIM+k]*hv;
    au += Uiou[(size_t)(2*HDIM+m)*HDIM+k]*hv;
  }
  float c = sigf(ai)*tanh_f(au) + rootacc[m];
  out[m] = sigf(ao)*tanh_f(c);
}

extern "C" void kernel_launch(void* const* d_in, const int* in_sizes, int n_in,
                              void* d_out, int out_size, void* d_ws, size_t ws_size,
                              hipStream_t stream)
{
  const int*   tok    = (const int*)d_in[0];
  const int*   parent = (const int*)d_in[1];
  const float* emb    = (const float*)d_in[4];
  const float* Wiou   = (const float*)d_in[5];
  const float* biou   = (const float*)d_in[6];
  const float* Uiou   = (const float*)d_in[7];
  const float* Wf     = (const float*)d_in[8];
  const float* bf     = (const float*)d_in[9];
  const float* Uf     = (const float*)d_in[10];
  float* out = (float*)d_out;

  char* w = (char*)d_ws;
  size_t SZF = (size_t)PER*HDIM*sizeof(float);
  size_t SZH = (size_t)PER*HDIM*sizeof(f16);
  float* cA      = (float*)w;            w += SZF;
  float* cB      = (float*)w;            w += SZF;
  float* FC      = (float*)w;            w += SZF;
  float* embWiou = (float*)w;            w += 1024*NIOU*sizeof(float);
  float* embWf   = (float*)w;            w += 1024*HDIM*sizeof(float);
  float* rootacc = (float*)w;            w += 128*sizeof(float);
  int*   counts  = (int*)w;              w += (size_t)PER*sizeof(int);
  int*   list    = (int*)w;              w += (size_t)PER*MAXC*sizeof(int);
  f16*   hA      = (f16*)w;              w += SZH;
  f16*   hB      = (f16*)w;              w += SZH;
  f16*   Bfpack  = (f16*)w;              w += 2*4*64*8*sizeof(f16);
  f16*   Biopack = (f16*)w;              w += 2*12*64*8*sizeof(f16);

  const int B = 256;
  const int gPER  = (PER + B - 1)/B;          // 586
  const int gLEAF = (PER*16 + B - 1)/B;
  const int gFCH  = (PER + 255)/256;          // 586 blocks x 4 waves x 64 children
  const int gNODE = (PER + 63)/64;            // 2341 blocks x 64 parents

  hipMemsetAsync(counts, 0, (size_t)PER*sizeof(int), stream);
  hipMemsetAsync(rootacc, 0, 128*sizeof(float), stream);
  table_kernel<<<1024, B, 0, stream>>>(emb, Wiou, biou, Wf, bf, embWiou, embWf);
  pack_kernel<<<1, B, 0, stream>>>(Uf, Uiou, Bfpack, Biopack);

  leaf_kernel<<<gLEAF, B, 0, stream>>>(tok, embWiou, hA, cA);

  f16* hPrev=hA; float* cPrev=cA; f16* hCur=hB; float* cCur=cB;
  for (int d=6; d>=1; --d){
    int poff = 1 + (d-1)*PER;
    int coff = 1 + d*PER;
    build_kernel<<<gPER, B, 0, stream>>>(parent, counts, list, coff, poff);
    fch_mfma   <<<gFCH, B, 0, stream>>>(tok, parent, embWf, Bfpack, hPrev, cPrev, FC, coff);
    node_mfma  <<<gNODE, B, 0, stream>>>(tok, embWiou, Biopack, counts, list, FC,
                                         hPrev, hCur, cCur, poff);
    f16* th=hPrev; hPrev=hCur; hCur=th;
    float* tc=cPrev; cPrev=cCur; cCur=tc;
  }

  // depth 0 (root)
  fch_mfma<<<gFCH, B, 0, stream>>>(tok, parent, embWf, Bfpack, hPrev, cPrev, FC, 1);
  rootred_kernel<<<256, B, 0, stream>>>(FC, hPrev, rootacc);
  rootnode_kernel<<<1, 64, 0, stream>>>(tok, emb, Wiou, biou, Uiou, rootacc, out);
}